// Round 9
// baseline (185.524 us; speedup 1.0000x reference)
//
#include <hip/hip_runtime.h>
#include <hip/hip_bf16.h>

#define N 8192
#define FIN 256
#define FOUT 128
#define ALPHA 0.2f

typedef unsigned short ushort_t;
typedef __attribute__((ext_vector_type(8))) short short8;
typedef __attribute__((ext_vector_type(4))) float f32x4;

#define GLOAD16(gp, lp)                                        \
  __builtin_amdgcn_global_load_lds(                            \
      (const __attribute__((address_space(1))) void*)(gp),     \
      (__attribute__((address_space(3))) void*)(lp), 16, 0, 0)

__device__ __forceinline__ ushort_t f2bf(float x) {
  __hip_bfloat16 b = __float2bfloat16(x);  // RNE
  return *reinterpret_cast<ushort_t*>(&b);
}

// ---------------- Kernel 1: h = X@W (fp32), s1 = h@a1, s2 = h@a2, hT = bf16(h)^T ----
__global__ __launch_bounds__(256) void k_h(const float* __restrict__ inp,
                                           const float* __restrict__ Wm,
                                           const float* __restrict__ av,
                                           ushort_t* __restrict__ hT,
                                           float* __restrict__ s1,
                                           float* __restrict__ s2) {
  __shared__ float in_lds[16][FIN];
  __shared__ float h_tile[16][FOUT];
  const int t = threadIdx.x;
  const int r0 = blockIdx.x * 16;

  for (int idx = t; idx < 16 * FIN; idx += 256) {
    int ii = idx >> 8, kk = idx & 255;
    in_lds[ii][kk] = inp[(size_t)(r0 + ii) * FIN + kk];
  }
  __syncthreads();

  const int c2 = (t & 63) * 2;
  const int rg = t >> 6;
  float acc[4][2] = {};
  for (int k = 0; k < FIN; k += 4) {
    float4 iv[4];
#pragma unroll
    for (int q = 0; q < 4; ++q)
      iv[q] = *reinterpret_cast<const float4*>(&in_lds[rg * 4 + q][k]);
#pragma unroll
    for (int kk = 0; kk < 4; ++kk) {
      float2 wp = *reinterpret_cast<const float2*>(&Wm[(size_t)(k + kk) * FOUT + c2]);
#pragma unroll
      for (int q = 0; q < 4; ++q) {
        float x = reinterpret_cast<const float*>(&iv[q])[kk];
        acc[q][0] = fmaf(x, wp.x, acc[q][0]);
        acc[q][1] = fmaf(x, wp.y, acc[q][1]);
      }
    }
  }
#pragma unroll
  for (int q = 0; q < 4; ++q) {
    h_tile[rg * 4 + q][c2] = acc[q][0];
    h_tile[rg * 4 + q][c2 + 1] = acc[q][1];
  }
  __syncthreads();

  const int wv_ = t >> 6, lane = t & 63;
#pragma unroll
  for (int rr = 0; rr < 4; ++rr) {
    int row = wv_ * 4 + rr;
    float h0 = h_tile[row][lane], h1 = h_tile[row][lane + 64];
    float p1 = h0 * av[lane] + h1 * av[lane + 64];
    float p2 = h0 * av[FOUT + lane] + h1 * av[FOUT + lane + 64];
#pragma unroll
    for (int m = 32; m; m >>= 1) {
      p1 += __shfl_xor(p1, m);
      p2 += __shfl_xor(p2, m);
    }
    if (lane == 0) { s1[r0 + row] = p1; s2[r0 + row] = p2; }
  }

  for (int idx = t; idx < 16 * FOUT; idx += 256) {
    int c = idx >> 4, ii = idx & 15;
    hT[(size_t)c * N + r0 + ii] = f2bf(h_tile[ii][c]);
  }
}

// ---------------- Kernel 1b: global max of s2 -------------------------------------
__global__ __launch_bounds__(256) void k_smax(const float* __restrict__ s2,
                                              float* __restrict__ outm) {
  __shared__ float red[4];
  const int t = threadIdx.x;
  float m = -1e30f;
  for (int i = t; i < N; i += 256) m = fmaxf(m, s2[i]);
#pragma unroll
  for (int d = 32; d; d >>= 1) m = fmaxf(m, __shfl_xor(m, d));
  if ((t & 63) == 0) red[t >> 6] = m;
  __syncthreads();
  if (t == 0) outm[0] = fmaxf(fmaxf(red[0], red[1]), fmaxf(red[2], red[3]));
}

// ---------------- Kernel 1c: softmax factor tables --------------------------------
// exp(leakyrelu(x) - mv) = max(exp(x-mv), exp(0.2x-mv)) = max(P_i*Q_j, R_i*S_j).
__global__ __launch_bounds__(256) void k_coef(const float* __restrict__ s1,
                                              const float* __restrict__ s2,
                                              const float* __restrict__ s2max,
                                              float2* __restrict__ QS,
                                              float2* __restrict__ PR) {
  const int i = blockIdx.x * 256 + threadIdx.x;
  const float smx = s2max[0];
  float s1v = s1[i];
  float pre = s1v + smx;
  float mv = pre > 0.f ? pre : ALPHA * pre;  // >= max_j leakyrelu(s1_i+s2_j)
  PR[i] = make_float2(__expf(s1v - mv), __expf(ALPHA * s1v - mv));
  float s2v = s2[i];
  QS[i] = make_float2(__expf(s2v), __expf(ALPHA * s2v));
}

// ---------------- Kernel 2: pack adj bits + per-row softmax denominator -----------
// r7's k_prep verbatim (proven free-running streaming regime): one wave per row,
// lane owns 32 consecutive j per pass (128 B contiguous). Deterministic reduce.
__global__ __launch_bounds__(512) void k_prep(const int* __restrict__ adj,
                                              const float* __restrict__ s1g,
                                              const float* __restrict__ s2g,
                                              const float* __restrict__ s2max,
                                              unsigned* __restrict__ maskRM,
                                              float* __restrict__ den) {
  const int t = threadIdx.x, lane = t & 63, w = t >> 6;
  const int r = blockIdx.x * 8 + w;
  const float s1v = s1g[r];
  const float mraw = s1v + s2max[0];
  const float mv = mraw > 0.f ? mraw : ALPHA * mraw;
  const float L2E = 1.44269504f;
  const float mvl = mv * L2E;
  const int* __restrict__ arow = adj + (size_t)r * N;
  float dacc = 0.f;

#pragma unroll
  for (int p = 0; p < 4; ++p) {
    const int j0 = p * 2048 + lane * 32;
    int4 a[8];
#pragma unroll
    for (int s = 0; s < 8; ++s) a[s] = *reinterpret_cast<const int4*>(arow + j0 + s * 4);
    float4 sv[8];
#pragma unroll
    for (int s = 0; s < 8; ++s) sv[s] = *reinterpret_cast<const float4*>(s2g + j0 + s * 4);
    unsigned wbits = 0;
#pragma unroll
    for (int s = 0; s < 8; ++s) {
      const int* ai = reinterpret_cast<const int*>(&a[s]);
      const float* sf = reinterpret_cast<const float*>(&sv[s]);
#pragma unroll
      for (int e = 0; e < 4; ++e) {
        float pre = s1v + sf[e];
        float lr = fmaxf(pre, ALPHA * pre);
        float ew = __builtin_amdgcn_exp2f(fmaf(lr, L2E, -mvl));
        bool on = ai[e] > 0;
        wbits |= (on ? 1u : 0u) << (s * 4 + e);
        dacc += on ? ew : 0.f;
      }
    }
    maskRM[(size_t)r * (N / 32) + p * 64 + lane] = wbits;  // coalesced
  }
#pragma unroll
  for (int m = 32; m; m >>= 1) dacc += __shfl_xor(dacc, m);
  if (lane == 0) den[r] = dacc;
}

// ---------------- Kernel 3: masked softmax numerator + P@h (r5 skeleton) ----------
// nchunks=4 -> 512 blocks, 2 blocks/CU (the r5 overlap property: one block's MFMA
// phase hides the other's stage-drain). Weights exp-free: max(Pv*Q, Rv*S) gated by
// bitmask — 5 VALU/weight, no dacc (den precomputed in k_prep).
__global__ __launch_bounds__(512, 4) void k_attn(const unsigned* __restrict__ maskRM,
                                                 const ushort_t* __restrict__ hT,
                                                 const float2* __restrict__ QS,
                                                 const float2* __restrict__ PR,
                                                 float* __restrict__ slab,
                                                 int jc, int ntiles) {
  __shared__ __align__(16) ushort_t Bt[32768];  // 64 KB staged hT tile

  const int t = threadIdx.x;
  const int lane = t & 63;
  const int wid = t >> 6;
  const int rb = blockIdx.x & 127;
  const int chunk = blockIdx.x >> 7;
  const int i0 = rb * 64;
  const int jc0 = chunk * jc;

  const int g = wid & 3;        // row-group
  const int hf = wid >> 2;      // j-half of tile
  const int arow = lane & 15;   // A-frag row / B-frag col
  const int kb = lane >> 4;     // k-slot 0..3
  const int irow = i0 + g * 16 + arow;

  const float2 pr = PR[irow];
  const float Pv = pr.x, Rv = pr.y;

  const unsigned* __restrict__ maskp =
      maskRM + (size_t)irow * (N / 32) + ((jc0 + hf * 128) >> 5);
  const float2* __restrict__ qsp = QS + jc0 + hf * 128 + kb * 8;
  const char* __restrict__ hTb = (const char*)hT;

  f32x4 acc[8];
#pragma unroll
  for (int ct = 0; ct < 8; ++ct) acc[ct] = (f32x4){0.f, 0.f, 0.f, 0.f};

  for (int jt = 0; jt < ntiles; ++jt) {
    const int j0 = jt * 256;

    // ---- stage hT[0:128][jc0+j0 : +256] -> Bt, linear dest + swizzled source ----
#pragma unroll
    for (int s = 0; s < 8; ++s) {
      int L = s * 512 + t;          // 16B-granule index
      int rr = L >> 5;              // ct row 0..127
      int boff = (L & 31) * 16;     // byte offset in 512B row
      const char* src =
          hTb + ((size_t)rr * N + jc0 + j0) * 2 + (boff ^ ((rr & 7) << 4));
      GLOAD16(src, (char*)Bt + L * 16);
    }

    // ---- mask words for this tile (4 words = kq 0..3 of this hf-half) ----
    int4 mw = *reinterpret_cast<const int4*>(maskp + (j0 >> 5));

    __syncthreads();  // Bt staged

#pragma unroll
    for (int kq = 0; kq < 4; ++kq) {
      // B-fragments from LDS (swizzled read)
      short8 bf[8];
      const int byte0 = hf * 256 + kq * 64 + kb * 16;
#pragma unroll
      for (int ct = 0; ct < 8; ++ct) {
        int row = ct * 16 + arow;
        int off = row * 512 + (byte0 ^ ((row & 7) << 4));
        bf[ct] = *reinterpret_cast<const short8*>((const char*)Bt + off);
      }
      // weights: w = mask ? max(Pv*Q_j, Rv*S_j) : 0   (no exp, no dacc)
      const unsigned word = (kq == 0) ? mw.x : (kq == 1) ? mw.y : (kq == 2) ? mw.z : mw.w;
      const unsigned w8 = (word >> (kb * 8)) & 0xffu;
      const float4* q4 = reinterpret_cast<const float4*>(qsp + j0 + kq * 32);
      float4 qa = q4[0], qb = q4[1], qc = q4[2], qd = q4[3];
      short8 af;
      float w;
      w = fmaxf(Pv * qa.x, Rv * qa.y); af[0] = (short)f2bf((w8 & 1u) ? w : 0.f);
      w = fmaxf(Pv * qa.z, Rv * qa.w); af[1] = (short)f2bf((w8 & 2u) ? w : 0.f);
      w = fmaxf(Pv * qb.x, Rv * qb.y); af[2] = (short)f2bf((w8 & 4u) ? w : 0.f);
      w = fmaxf(Pv * qb.z, Rv * qb.w); af[3] = (short)f2bf((w8 & 8u) ? w : 0.f);
      w = fmaxf(Pv * qc.x, Rv * qc.y); af[4] = (short)f2bf((w8 & 16u) ? w : 0.f);
      w = fmaxf(Pv * qc.z, Rv * qc.w); af[5] = (short)f2bf((w8 & 32u) ? w : 0.f);
      w = fmaxf(Pv * qd.x, Rv * qd.y); af[6] = (short)f2bf((w8 & 64u) ? w : 0.f);
      w = fmaxf(Pv * qd.z, Rv * qd.w); af[7] = (short)f2bf((w8 & 128u) ? w : 0.f);

#pragma unroll
      for (int ct = 0; ct < 8; ++ct)
        acc[ct] = __builtin_amdgcn_mfma_f32_16x16x32_bf16(af, bf[ct], acc[ct], 0, 0, 0);
    }

    __syncthreads();  // all waves done reading Bt before next stage
  }

  // ---- combine the two hf-halves' k-partials in LDS (reuse Bt) ----
  float (*Hred)[132] = (float(*)[132])(void*)Bt;  // 64 x 132 x 4B
  // C/D layout (m89-verified): col = ct*16 + arow, row-in-group = kb*4 + r
  if (hf == 0) {
#pragma unroll
    for (int ct = 0; ct < 8; ++ct)
#pragma unroll
      for (int r = 0; r < 4; ++r)
        Hred[g * 16 + kb * 4 + r][ct * 16 + arow] = acc[ct][r];
  }
  __syncthreads();
  if (hf == 1) {
#pragma unroll
    for (int ct = 0; ct < 8; ++ct)
#pragma unroll
      for (int r = 0; r < 4; ++r)
        Hred[g * 16 + kb * 4 + r][ct * 16 + arow] += acc[ct][r];
  }
  __syncthreads();

  for (int idx = t; idx < 64 * 128; idx += 512) {
    int r = idx >> 7, c = idx & 127;
    slab[((size_t)chunk * N + i0 + r) * 128 + c] = Hred[r][c];
  }
}

// ---------------- Kernel 4: combine chunks, divide by den, ELU --------------------
__global__ __launch_bounds__(256) void k_fin(const float* __restrict__ slab,
                                             const float* __restrict__ den,
                                             float* __restrict__ out, int nchunks) {
  const int idx = blockIdx.x * 256 + threadIdx.x;  // < N*FOUT
  const int i = idx >> 7;
  float v = 0.f;
  for (int k = 0; k < nchunks; ++k) v += slab[(size_t)k * N * FOUT + idx];
  v /= den[i];
  out[idx] = v > 0.f ? v : (__expf(v) - 1.f);
}

extern "C" void kernel_launch(void* const* d_in, const int* in_sizes, int n_in,
                              void* d_out, int out_size, void* d_ws, size_t ws_size,
                              hipStream_t stream) {
  const float* inp = (const float*)d_in[0];   // [N][FIN] fp32
  const int* adj   = (const int*)d_in[1];     // [N][N] int32
  const float* Wm  = (const float*)d_in[2];   // [FIN][FOUT] fp32
  const float* av  = (const float*)d_in[3];   // [2*FOUT] fp32
  float* out = (float*)d_out;

  // workspace carve-up
  char* ws = (char*)d_ws;
  ushort_t* hT = (ushort_t*)ws;                               // 2 MB
  float* s1    = (float*)(ws + (size_t)FOUT * N * 2);         // 32 KB
  float* s2    = s1 + N;                                      // 32 KB
  float* s2mx  = s2 + N;                                      // 16 B
  float* den   = s2mx + 4;                                    // 32 KB
  float2* QS   = (float2*)(den + N);                          // 64 KB
  float2* PR   = QS + N;                                      // 64 KB
  unsigned* maskRM = (unsigned*)(PR + N);                     // 8 MB
  float* slab  = (float*)(maskRM + (size_t)N * N / 32);

  const size_t base = (size_t)FOUT * N * 2 + (size_t)N * 4 * 3 + 16 +
                      (size_t)N * 16 + (size_t)N * N / 8;
  int nchunks = 4;
  while (nchunks > 1) {
    size_t need = base + (size_t)nchunks * N * FOUT * 4;
    if (need <= ws_size) break;
    nchunks >>= 1;
  }
  const int jc = N / nchunks;
  const int ntiles = jc / 256;

  k_h<<<N / 16, 256, 0, stream>>>(inp, Wm, av, hT, s1, s2);
  k_smax<<<1, 256, 0, stream>>>(s2, s2mx);
  k_coef<<<N / 256, 256, 0, stream>>>(s1, s2, s2mx, QS, PR);
  k_prep<<<N / 8, 512, 0, stream>>>(adj, s1, s2, s2mx, maskRM, den);
  k_attn<<<128 * nchunks, 512, 0, stream>>>(maskRM, hT, QS, PR, slab, jc, ntiles);
  k_fin<<<(N * FOUT) / 256, 256, 0, stream>>>(slab, den, out, nchunks);
}

// Round 10
// 148.924 us; speedup vs baseline: 1.2458x; 1.2458x over previous
//
#include <hip/hip_runtime.h>
#include <hip/hip_bf16.h>

#define N 8192
#define FIN 256
#define FOUT 128
#define ALPHA 0.2f

typedef unsigned short ushort_t;
typedef __attribute__((ext_vector_type(8))) short short8;
typedef __attribute__((ext_vector_type(4))) float f32x4;
typedef __attribute__((ext_vector_type(16))) float f32x16;

#define GLOAD16(gp, lp)                                        \
  __builtin_amdgcn_global_load_lds(                            \
      (const __attribute__((address_space(1))) void*)(gp),     \
      (__attribute__((address_space(3))) void*)(lp), 16, 0, 0)

__device__ __forceinline__ ushort_t f2bf(float x) {
  __hip_bfloat16 b = __float2bfloat16(x);  // RNE
  return *reinterpret_cast<ushort_t*>(&b);
}

// ---------------- Kernel 1: fused {h = X@W, s1, s2, hT} + adj bitpack -------------
// Blocks [0,512): k_h. Blocks [512,2048): contiguous grid-stride pack of adj>0
// into the 8 MB bitmask (the proven ~5.6 TB/s streaming shape; k_h hides under it).
__global__ __launch_bounds__(256) void k_fh(const float* __restrict__ inp,
                                            const float* __restrict__ Wm,
                                            const float* __restrict__ av,
                                            const int* __restrict__ adj,
                                            ushort_t* __restrict__ hT,
                                            float* __restrict__ s1,
                                            float* __restrict__ s2,
                                            unsigned* __restrict__ maskRM) {
  __shared__ float in_lds[16][FIN];
  __shared__ float h_tile[16][FOUT];
  const int t = threadIdx.x;

  if (blockIdx.x >= 512) {
    const size_t tid = (size_t)(blockIdx.x - 512) * 256 + t;
    const size_t nthr = (size_t)(gridDim.x - 512) * 256;
    const size_t nwords = (size_t)N * (N / 32);
    for (size_t w = tid; w < nwords; w += nthr) {
      const int4* p = reinterpret_cast<const int4*>(adj + w * 32);
      unsigned m = 0;
#pragma unroll
      for (int s = 0; s < 8; ++s) {
        int4 v = p[s];
        m |= (v.x > 0 ? 1u : 0u) << (s * 4);
        m |= (v.y > 0 ? 1u : 0u) << (s * 4 + 1);
        m |= (v.z > 0 ? 1u : 0u) << (s * 4 + 2);
        m |= (v.w > 0 ? 1u : 0u) << (s * 4 + 3);
      }
      maskRM[w] = m;
    }
    return;
  }

  const int r0 = blockIdx.x * 16;
  for (int idx = t; idx < 16 * FIN; idx += 256) {
    int ii = idx >> 8, kk = idx & 255;
    in_lds[ii][kk] = inp[(size_t)(r0 + ii) * FIN + kk];
  }
  __syncthreads();

  const int c2 = (t & 63) * 2;
  const int rg = t >> 6;
  float acc[4][2] = {};
  for (int k = 0; k < FIN; k += 4) {
    float4 iv[4];
#pragma unroll
    for (int q = 0; q < 4; ++q)
      iv[q] = *reinterpret_cast<const float4*>(&in_lds[rg * 4 + q][k]);
#pragma unroll
    for (int kk = 0; kk < 4; ++kk) {
      float2 wp = *reinterpret_cast<const float2*>(&Wm[(size_t)(k + kk) * FOUT + c2]);
#pragma unroll
      for (int q = 0; q < 4; ++q) {
        float x = reinterpret_cast<const float*>(&iv[q])[kk];
        acc[q][0] = fmaf(x, wp.x, acc[q][0]);
        acc[q][1] = fmaf(x, wp.y, acc[q][1]);
      }
    }
  }
#pragma unroll
  for (int q = 0; q < 4; ++q) {
    h_tile[rg * 4 + q][c2] = acc[q][0];
    h_tile[rg * 4 + q][c2 + 1] = acc[q][1];
  }
  __syncthreads();

  const int wv_ = t >> 6, lane = t & 63;
#pragma unroll
  for (int rr = 0; rr < 4; ++rr) {
    int row = wv_ * 4 + rr;
    float h0 = h_tile[row][lane], h1 = h_tile[row][lane + 64];
    float p1 = h0 * av[lane] + h1 * av[lane + 64];
    float p2 = h0 * av[FOUT + lane] + h1 * av[FOUT + lane + 64];
#pragma unroll
    for (int m = 32; m; m >>= 1) {
      p1 += __shfl_xor(p1, m);
      p2 += __shfl_xor(p2, m);
    }
    if (lane == 0) { s1[r0 + row] = p1; s2[r0 + row] = p2; }
  }

  for (int idx = t; idx < 16 * FOUT; idx += 256) {
    int c = idx >> 4, ii = idx & 15;
    hT[(size_t)c * N + r0 + ii] = f2bf(h_tile[ii][c]);
  }
}

// ---------------- Kernel 1b: global max of s2 -------------------------------------
__global__ __launch_bounds__(256) void k_smax(const float* __restrict__ s2,
                                              float* __restrict__ outm) {
  __shared__ float red[4];
  const int t = threadIdx.x;
  float m = -1e30f;
  for (int i = t; i < N; i += 256) m = fmaxf(m, s2[i]);
#pragma unroll
  for (int d = 32; d; d >>= 1) m = fmaxf(m, __shfl_xor(m, d));
  if ((t & 63) == 0) red[t >> 6] = m;
  __syncthreads();
  if (t == 0) outm[0] = fmaxf(fmaxf(red[0], red[1]), fmaxf(red[2], red[3]));
}

// ---------------- Kernel 1c: softmax factor tables --------------------------------
// exp(leakyrelu(x) - mv) = max(exp(x-mv), exp(0.2x-mv)) = max(P_i*Q_j, R_i*S_j).
__global__ __launch_bounds__(256) void k_coef(const float* __restrict__ s1,
                                              const float* __restrict__ s2,
                                              const float* __restrict__ s2max,
                                              float2* __restrict__ QS,
                                              float2* __restrict__ PR) {
  const int i = blockIdx.x * 256 + threadIdx.x;
  const float smx = s2max[0];
  float s1v = s1[i];
  float pre = s1v + smx;
  float mv = pre > 0.f ? pre : ALPHA * pre;  // >= max_j leakyrelu(s1_i+s2_j)
  PR[i] = make_float2(__expf(s1v - mv), __expf(ALPHA * s1v - mv));
  float s2v = s2[i];
  QS[i] = make_float2(__expf(s2v), __expf(ALPHA * s2v));
}

// ---------------- Kernel 2: masked softmax + P@h, 32x32x16 MFMA -------------------
// r5/r8 skeleton (stage hT tile once into swizzled LDS, 8 waves share, 2 blk/CU)
// but with mfma_f32_32x32x16_bf16: each B-fragment b128 feeds 32 output cols ->
// LDS reads per tile HALVED (the modeled bottleneck). Swizzle (row&15)<<4 keeps
// the 32-row read pattern <=2-way. Wave (g2=wid&1, hf=wid>>1): rows g2*32..+32,
// j-quarter hf*64 of each 256-tile. Weights exp-free; dacc inline (r8-proven).
__global__ __launch_bounds__(512, 4) void k_attn(const unsigned* __restrict__ maskRM,
                                                 const ushort_t* __restrict__ hT,
                                                 const float2* __restrict__ QS,
                                                 const float2* __restrict__ PR,
                                                 float* __restrict__ slab,
                                                 float* __restrict__ denp,
                                                 int jc, int ntiles) {
  __shared__ __align__(16) ushort_t Bt[32768];  // 64 KB staged hT tile
  __shared__ float Dred[8][32];

  const int t = threadIdx.x;
  const int lane = t & 63;
  const int wid = t >> 6;
  const int rb = blockIdx.x & 127;
  const int chunk = blockIdx.x >> 7;
  const int i0 = rb * 64;
  const int jc0 = chunk * jc;

  const int g2 = wid & 1;       // row-half (32 rows)
  const int hf = wid >> 1;      // j-quarter (64 j) of the 256-tile
  const int ar32 = lane & 31;   // A row / B col
  const int hi = lane >> 5;     // k half-slot
  const int irow = i0 + g2 * 32 + ar32;

  const float2 pr = PR[irow];
  const float Pv = pr.x, Rv = pr.y;

  const unsigned* __restrict__ maskp = maskRM + (size_t)irow * (N / 32) + (jc0 >> 5);
  const float2* __restrict__ qsp = QS + jc0 + hf * 64 + hi * 8;
  const char* __restrict__ hTb = (const char*)hT;

  f32x16 acc0 = {}, acc1 = {}, acc2 = {}, acc3 = {};
  float dacc = 0.f;

  for (int jt = 0; jt < ntiles; ++jt) {
    const int j0 = jt * 256;

    // ---- stage hT[0:128][jc0+j0:+256] -> Bt, linear dest + (&15)-swizzled src ----
#pragma unroll
    for (int s = 0; s < 8; ++s) {
      int L = s * 512 + t;          // 16B-granule index
      int rr = L >> 5;              // channel row 0..127
      int boff = (L & 31) * 16;     // byte offset in 512B row
      const char* src =
          hTb + ((size_t)rr * N + jc0 + j0) * 2 + (boff ^ ((rr & 15) << 4));
      GLOAD16(src, (char*)Bt + L * 16);
    }

    // ---- mask words for this wave's 64-j quarter (2 words) ----
    int2 mw = *reinterpret_cast<const int2*>(maskp + (j0 >> 5) + hf * 2);

    __syncthreads();  // Bt staged

#pragma unroll
    for (int kq = 0; kq < 4; ++kq) {  // 4 x 16-j K-steps within the quarter
      // weights -> A-fragment (row ar32, j = jc0+j0+hf*64+kq*16+hi*8+e)
      const unsigned word = (kq & 2) ? (unsigned)mw.y : (unsigned)mw.x;
      const unsigned w8 = (word >> ((kq & 1) * 16 + hi * 8)) & 0xffu;
      const float4* q4 = reinterpret_cast<const float4*>(qsp + j0 + kq * 16);
      float4 qa = q4[0], qb = q4[1], qc = q4[2], qd = q4[3];
      short8 af;
      float w;
      w = fmaxf(Pv * qa.x, Rv * qa.y); w = (w8 & 1u) ? w : 0.f; dacc += w; af[0] = (short)f2bf(w);
      w = fmaxf(Pv * qa.z, Rv * qa.w); w = (w8 & 2u) ? w : 0.f; dacc += w; af[1] = (short)f2bf(w);
      w = fmaxf(Pv * qb.x, Rv * qb.y); w = (w8 & 4u) ? w : 0.f; dacc += w; af[2] = (short)f2bf(w);
      w = fmaxf(Pv * qb.z, Rv * qb.w); w = (w8 & 8u) ? w : 0.f; dacc += w; af[3] = (short)f2bf(w);
      w = fmaxf(Pv * qc.x, Rv * qc.y); w = (w8 & 16u) ? w : 0.f; dacc += w; af[4] = (short)f2bf(w);
      w = fmaxf(Pv * qc.z, Rv * qc.w); w = (w8 & 32u) ? w : 0.f; dacc += w; af[5] = (short)f2bf(w);
      w = fmaxf(Pv * qd.x, Rv * qd.y); w = (w8 & 64u) ? w : 0.f; dacc += w; af[6] = (short)f2bf(w);
      w = fmaxf(Pv * qd.z, Rv * qd.w); w = (w8 & 128u) ? w : 0.f; dacc += w; af[7] = (short)f2bf(w);

      // B-fragments from swizzled LDS; one b128 per 32-col block; MFMA immediately
      const int byte0 = hf * 128 + kq * 32 + hi * 16;
      {
        int row = 0 * 32 + ar32;
        short8 bf = *reinterpret_cast<const short8*>(
            (const char*)Bt + row * 512 + (byte0 ^ ((row & 15) << 4)));
        acc0 = __builtin_amdgcn_mfma_f32_32x32x16_bf16(af, bf, acc0, 0, 0, 0);
      }
      {
        int row = 1 * 32 + ar32;
        short8 bf = *reinterpret_cast<const short8*>(
            (const char*)Bt + row * 512 + (byte0 ^ ((row & 15) << 4)));
        acc1 = __builtin_amdgcn_mfma_f32_32x32x16_bf16(af, bf, acc1, 0, 0, 0);
      }
      {
        int row = 2 * 32 + ar32;
        short8 bf = *reinterpret_cast<const short8*>(
            (const char*)Bt + row * 512 + (byte0 ^ ((row & 15) << 4)));
        acc2 = __builtin_amdgcn_mfma_f32_32x32x16_bf16(af, bf, acc2, 0, 0, 0);
      }
      {
        int row = 3 * 32 + ar32;
        short8 bf = *reinterpret_cast<const short8*>(
            (const char*)Bt + row * 512 + (byte0 ^ ((row & 15) << 4)));
        acc3 = __builtin_amdgcn_mfma_f32_32x32x16_bf16(af, bf, acc3, 0, 0, 0);
      }
    }

    __syncthreads();  // all waves done reading Bt before next stage
  }

  // ---- denominator partials: lanes l and l+32 share row ar32 ----
  dacc += __shfl_xor(dacc, 32);
  if (lane < 32) Dred[wid][lane] = dacc;

  // ---- cross-wave (hf) reduction of k-partials in LDS (reuse Bt) ----
  float (*Hred)[132] = (float(*)[132])(void*)Bt;  // 64 x 132 x 4B = 33.8 KB
  // C/D layout 32x32 (m74/m101): col = lane&31, row = (reg&3)+8*(reg>>2)+4*hi
  for (int wv = 0; wv < 4; ++wv) {
    if (hf == wv) {
#pragma unroll
      for (int reg = 0; reg < 16; ++reg) {
        int rl = (reg & 3) + 8 * (reg >> 2) + 4 * hi;
        int rr = g2 * 32 + rl;
        if (wv == 0) {
          Hred[rr][0 * 32 + ar32] = acc0[reg];
          Hred[rr][1 * 32 + ar32] = acc1[reg];
          Hred[rr][2 * 32 + ar32] = acc2[reg];
          Hred[rr][3 * 32 + ar32] = acc3[reg];
        } else {
          Hred[rr][0 * 32 + ar32] += acc0[reg];
          Hred[rr][1 * 32 + ar32] += acc1[reg];
          Hred[rr][2 * 32 + ar32] += acc2[reg];
          Hred[rr][3 * 32 + ar32] += acc3[reg];
        }
      }
    }
    __syncthreads();
  }

  if (t < 64) {
    int gg = t >> 5, rl = t & 31;
    denp[(size_t)chunk * N + i0 + t] =
        Dred[gg][rl] + Dred[2 + gg][rl] + Dred[4 + gg][rl] + Dred[6 + gg][rl];
  }

  for (int idx = t; idx < 64 * 128; idx += 512) {
    int r = idx >> 7, c = idx & 127;
    slab[((size_t)chunk * N + i0 + r) * 128 + c] = Hred[r][c];
  }
}

// ---------------- Kernel 3: combine chunks, divide, ELU ---------------------------
__global__ __launch_bounds__(256) void k_fin(const float* __restrict__ slab,
                                             const float* __restrict__ denp,
                                             float* __restrict__ out, int nchunks) {
  const int idx = blockIdx.x * 256 + threadIdx.x;  // < N*FOUT
  const int i = idx >> 7;
  float den = 0.f, v = 0.f;
  for (int k = 0; k < nchunks; ++k) {
    den += denp[(size_t)k * N + i];
    v += slab[(size_t)k * N * FOUT + idx];
  }
  v /= den;
  out[idx] = v > 0.f ? v : (__expf(v) - 1.f);
}

extern "C" void kernel_launch(void* const* d_in, const int* in_sizes, int n_in,
                              void* d_out, int out_size, void* d_ws, size_t ws_size,
                              hipStream_t stream) {
  const float* inp = (const float*)d_in[0];   // [N][FIN] fp32
  const int* adj   = (const int*)d_in[1];     // [N][N] int32
  const float* Wm  = (const float*)d_in[2];   // [FIN][FOUT] fp32
  const float* av  = (const float*)d_in[3];   // [2*FOUT] fp32
  float* out = (float*)d_out;

  // workspace carve-up
  char* ws = (char*)d_ws;
  ushort_t* hT = (ushort_t*)ws;                               // 2 MB
  float* s1    = (float*)(ws + (size_t)FOUT * N * 2);         // 32 KB
  float* s2    = s1 + N;                                      // 32 KB
  float* s2mx  = s2 + N;                                      // 16 B
  float2* QS   = (float2*)(s2mx + 4);                         // 64 KB
  float2* PR   = QS + N;                                      // 64 KB
  unsigned* maskRM = (unsigned*)(PR + N);                     // 8 MB
  float* slab  = (float*)(maskRM + (size_t)N * N / 32);

  const size_t base = (size_t)FOUT * N * 2 + (size_t)N * 4 * 2 + 16 +
                      (size_t)N * 16 + (size_t)N * N / 8;
  int nchunks = 4;  // 512 blocks = 2 blk/CU (r5-proven overlap); ws inferred >=26.5MB
  while (nchunks > 1) {
    size_t need = base + (size_t)nchunks * ((size_t)N * FOUT * 4 + N * 4);
    if (need <= ws_size) break;
    nchunks >>= 1;
  }
  float* denp = slab + (size_t)nchunks * N * FOUT;
  const int jc = N / nchunks;
  const int ntiles = jc / 256;

  k_fh<<<2048, 256, 0, stream>>>(inp, Wm, av, adj, hT, s1, s2, maskRM);
  k_smax<<<1, 256, 0, stream>>>(s2, s2mx);
  k_coef<<<N / 256, 256, 0, stream>>>(s1, s2, s2mx, QS, PR);
  k_attn<<<128 * nchunks, 512, 0, stream>>>(maskRM, hT, QS, PR, slab, denp, jc, ntiles);
  k_fin<<<(N * FOUT) / 256, 256, 0, stream>>>(slab, denp, out, nchunks);
}